// Round 4
// baseline (135.505 us; speedup 1.0000x reference)
//
#include <hip/hip_runtime.h>
#include <stdint.h>

#define NB 64
#define NN 1024
#define CDIM 512
#define KK 64

typedef __attribute__((ext_vector_type(4))) float f32x4;
typedef __attribute__((ext_vector_type(8))) short short8;

__device__ __forceinline__ unsigned short f2bf(float f) {
  unsigned int u = __float_as_uint(f);
  return (unsigned short)((u + 0x7fffu + ((u >> 16) & 1u)) >> 16);
}

// ---------------- K0: centers fp32 -> bf16 ----------------
__global__ __launch_bounds__(256) void k0_cvt(const float* __restrict__ cc,
                                              unsigned short* __restrict__ ccb) {
  int i = blockIdx.x * 256 + threadIdx.x;   // grid sized exactly KK*CDIM/256
  ccb[i] = f2bf(cc[i]);
}

// ---- K1: logits (MFMA) + softmax + a^T (bf16) + a_sum + xT (bf16, [b][c][n]) ----
// grid: (16 n-chunks, 64 b), 256 threads = 4 waves, wave owns 16 n-rows.
// The bf16 A-fragments (x rows) are reused: transposed through a 16 KB LDS slab
// (128 c x 64 n, word-XOR swizzle by ((c>>3)&3)) and stored as xT for k2.
__global__ __launch_bounds__(256) void k1_assign(const float* __restrict__ x,
    const unsigned short* __restrict__ ccb, unsigned short* __restrict__ a_t,
    unsigned short* __restrict__ xTg, float* __restrict__ a_sum) {
  const int b = blockIdx.y;
  const int n0 = blockIdx.x << 6;
  const int tid = threadIdx.x;
  const int w = tid >> 6;
  const int l = tid & 63;
  const int lr = l & 15;
  const int lg = l >> 4;

  __shared__ unsigned short a_sm[KK * 64];     // [kc][r], byte-swizzled
  __shared__ unsigned short xT_sm[128 * 64];   // [c_loc][n], n^(((c>>3)&3)<<4)

  const float* xr = x + ((size_t)b * NN + n0 + (w << 4) + lr) * CDIM + (lg << 3);
  const unsigned short* cb = ccb + lr * CDIM + (lg << 3);
  const int n_l = (w << 4) + lr;

  f32x4 acc0 = {0.f, 0.f, 0.f, 0.f}, acc1 = acc0, acc2 = acc0, acc3 = acc0;

  for (int sl = 0; sl < 4; ++sl) {
    #pragma unroll
    for (int css = 0; css < 128; css += 32) {
      const int cs = (sl << 7) + css;
      f32x4 xa = *(const f32x4*)(xr + cs);
      f32x4 xb = *(const f32x4*)(xr + cs + 4);
      short8 af;
      af[0] = (short)f2bf(xa[0]); af[1] = (short)f2bf(xa[1]);
      af[2] = (short)f2bf(xa[2]); af[3] = (short)f2bf(xa[3]);
      af[4] = (short)f2bf(xb[0]); af[5] = (short)f2bf(xb[1]);
      af[6] = (short)f2bf(xb[2]); af[7] = (short)f2bf(xb[3]);
      short8 b0 = *(const short8*)(cb + cs);
      short8 b1 = *(const short8*)(cb + 16 * CDIM + cs);
      short8 b2 = *(const short8*)(cb + 32 * CDIM + cs);
      short8 b3 = *(const short8*)(cb + 48 * CDIM + cs);
      acc0 = __builtin_amdgcn_mfma_f32_16x16x32_bf16(af, b0, acc0, 0, 0, 0);
      acc1 = __builtin_amdgcn_mfma_f32_16x16x32_bf16(af, b1, acc1, 0, 0, 0);
      acc2 = __builtin_amdgcn_mfma_f32_16x16x32_bf16(af, b2, acc2, 0, 0, 0);
      acc3 = __builtin_amdgcn_mfma_f32_16x16x32_bf16(af, b3, acc3, 0, 0, 0);
      // transpose: lane's 8 bf16 (row n_l, cols c_l..c_l+7) -> xT slab
      #pragma unroll
      for (int i = 0; i < 8; ++i) {
        int c_l = css + (lg << 3) + i;
        xT_sm[(c_l << 6) + (n_l ^ (((c_l >> 3) & 3) << 4))] = (unsigned short)af[i];
      }
    }
    __syncthreads();
    // store slab: xTg[b][sl*128 + row][n0 + 2*wi .. +2], coalesced 128 B/row
    {
      const unsigned int* xs32 = (const unsigned int*)xT_sm;
      int wi = tid & 31, r0 = tid >> 5;
      size_t gbase = (((size_t)b * CDIM + (sl << 7)) << 10) + n0;
      #pragma unroll
      for (int it = 0; it < 16; ++it) {
        int row = (it << 3) + r0;
        unsigned int v = xs32[(row << 5) + (wi ^ (((row >> 3) & 3) << 3))];
        *((unsigned int*)(xTg + gbase + ((size_t)row << 10)) + wi) = v;
      }
    }
    __syncthreads();
  }

  // D layout: lane holds logits[row=(l>>4)*4+j][kc=t*16+(l&15)] in acc_t[j]
  const int swzb = (lr & 7) << 3;
  float s0 = 0.f, s1 = 0.f, s2 = 0.f, s3 = 0.f;
  #pragma unroll
  for (int j = 0; j < 4; ++j) {
    float m = fmaxf(fmaxf(acc0[j], acc1[j]), fmaxf(acc2[j], acc3[j]));
    m = fmaxf(m, __shfl_xor(m, 1));
    m = fmaxf(m, __shfl_xor(m, 2));
    m = fmaxf(m, __shfl_xor(m, 4));
    m = fmaxf(m, __shfl_xor(m, 8));
    float e0 = __expf(acc0[j] - m);
    float e1 = __expf(acc1[j] - m);
    float e2 = __expf(acc2[j] - m);
    float e3 = __expf(acc3[j] - m);
    float s = e0 + e1 + e2 + e3;
    s += __shfl_xor(s, 1); s += __shfl_xor(s, 2);
    s += __shfl_xor(s, 4); s += __shfl_xor(s, 8);
    float inv = 1.0f / s;
    e0 *= inv; e1 *= inv; e2 *= inv; e3 *= inv;
    int r = (w << 4) + (lg << 2) + j;
    int rs = r ^ swzb;
    a_sm[( lr       << 6) + rs] = f2bf(e0);
    a_sm[((16 + lr) << 6) + rs] = f2bf(e1);
    a_sm[((32 + lr) << 6) + rs] = f2bf(e2);
    a_sm[((48 + lr) << 6) + rs] = f2bf(e3);
    s0 += e0; s1 += e1; s2 += e2; s3 += e3;
  }
  s0 += __shfl_xor(s0, 16); s0 += __shfl_xor(s0, 32);
  s1 += __shfl_xor(s1, 16); s1 += __shfl_xor(s1, 32);
  s2 += __shfl_xor(s2, 16); s2 += __shfl_xor(s2, 32);
  s3 += __shfl_xor(s3, 16); s3 += __shfl_xor(s3, 32);
  if (lg == 0) {
    atomicAdd(&a_sum[(b << 6) + lr],      s0);
    atomicAdd(&a_sum[(b << 6) + 16 + lr], s1);
    atomicAdd(&a_sum[(b << 6) + 32 + lr], s2);
    atomicAdd(&a_sum[(b << 6) + 48 + lr], s3);
  }
  __syncthreads();
  const unsigned int* au = (const unsigned int*)a_sm;
  for (int e = tid; e < 2048; e += 256) {
    int kc = e >> 5, n2 = e & 31;
    unsigned int v = au[(kc << 5) + (n2 ^ ((kc & 7) << 2))];
    *((unsigned int*)(a_t + (((size_t)((b << 6) + kc)) << 10) + n0) + n2) = v;
  }
}

// ---- K2: pure-streaming MFMA: agg = a^T x, vlad = agg - a_sum*cc, sumsq ----
// grid: (8 c-slices, 2 k-halves, 64 b) = 1024 blocks, 256 thr = 4 waves.
// No LDS, no barriers: A-frags from a_t[b][k][n], B-frags from xT[b][c][n],
// both contract-contiguous short8 loads (L2/L3-hot).
__global__ __launch_bounds__(256) void k2_agg(
    const unsigned short* __restrict__ a_t, const unsigned short* __restrict__ xTg,
    const float* __restrict__ cc, const float* __restrict__ a_sum,
    float* __restrict__ out, float* __restrict__ sumsq) {
  const int cs = blockIdx.x;
  const int kq = blockIdx.y;
  const int b  = blockIdx.z;
  const int tid = threadIdx.x;
  const int w = tid >> 6;
  const int l = tid & 63;
  const int lr = l & 15;
  const int lg = l >> 4;
  const int ct = (cs << 6) + (w << 4);   // wave's c-tile base

  const unsigned short* ap0 =
      a_t + (((size_t)((b << 6) + (kq << 5) + lr)) << 10) + (lg << 3);
  const unsigned short* ap1 = ap0 + (16 << 10);
  const unsigned short* bp =
      xTg + (((size_t)(b * CDIM + ct + lr)) << 10) + (lg << 3);

  f32x4 acc0 = {0.f, 0.f, 0.f, 0.f}, acc1 = acc0;

  #pragma unroll 4
  for (int ns = 0; ns < NN; ns += 64) {
    short8 bf0 = *(const short8*)(bp + ns);
    short8 bf1 = *(const short8*)(bp + ns + 32);
    short8 a00 = *(const short8*)(ap0 + ns);
    short8 a10 = *(const short8*)(ap1 + ns);
    short8 a01 = *(const short8*)(ap0 + ns + 32);
    short8 a11 = *(const short8*)(ap1 + ns + 32);
    acc0 = __builtin_amdgcn_mfma_f32_16x16x32_bf16(a00, bf0, acc0, 0, 0, 0);
    acc1 = __builtin_amdgcn_mfma_f32_16x16x32_bf16(a10, bf0, acc1, 0, 0, 0);
    acc0 = __builtin_amdgcn_mfma_f32_16x16x32_bf16(a01, bf1, acc0, 0, 0, 0);
    acc1 = __builtin_amdgcn_mfma_f32_16x16x32_bf16(a11, bf1, acc1, 0, 0, 0);
  }

  // epilogue: D[row=k][col=c]; tile t: k = kq*32 + t*16 + lg*4 + j, c = ct + lr
  float lsum = 0.f;
  #pragma unroll
  for (int j = 0; j < 4; ++j) {
    int k0i = (kq << 5) + (lg << 2) + j;
    int c = ct + lr;
    float v0 = acc0[j] - a_sum[(b << 6) + k0i] * cc[k0i * CDIM + c];
    out[((size_t)b << 15) + (k0i << 9) + c] = v0;
    lsum += v0 * v0;
    int k1i = k0i + 16;
    float v1 = acc1[j] - a_sum[(b << 6) + k1i] * cc[k1i * CDIM + c];
    out[((size_t)b << 15) + (k1i << 9) + c] = v1;
    lsum += v1 * v1;
  }
  lsum += __shfl_xor(lsum, 1);  lsum += __shfl_xor(lsum, 2);
  lsum += __shfl_xor(lsum, 4);  lsum += __shfl_xor(lsum, 8);
  lsum += __shfl_xor(lsum, 16); lsum += __shfl_xor(lsum, 32);
  if (l == 0) atomicAdd(&sumsq[b], lsum);
}

// ---------------- K3: l2 normalize per batch ----------------
__global__ __launch_bounds__(256) void k3_norm(float* __restrict__ out,
                                               const float* __restrict__ sumsq) {
  int idx = blockIdx.x * 256 + threadIdx.x;   // grid exact: 2048*256 = 2M/4
  int b = idx >> 13;                          // 8192 float4 per batch
  float s = sumsq[b];
  float scale = 1.0f / sqrtf(fmaxf(s, 1e-12f));
  f32x4* io = (f32x4*)out;
  f32x4 v = io[idx];
  v[0] *= scale; v[1] *= scale; v[2] *= scale; v[3] *= scale;
  io[idx] = v;
}

extern "C" void kernel_launch(void* const* d_in, const int* in_sizes, int n_in,
                              void* d_out, int out_size, void* d_ws, size_t ws_size,
                              hipStream_t stream) {
  const float* x  = (const float*)d_in[0];
  const float* cc = (const float*)d_in[1];
  float* out = (float*)d_out;
  char* ws = (char*)d_ws;
  // ws: [a_t bf16 8MiB][ccb 64KiB][a_sum 16KiB][sumsq 256B] ... [xT bf16 64MiB @16MiB]
  unsigned short* a_t = (unsigned short*)ws;
  unsigned short* ccb = (unsigned short*)(ws + (8u << 20));
  float* a_sum = (float*)(ws + (8u << 20) + (64u << 10));
  float* sumsq = a_sum + NB * KK;
  unsigned short* xTg = (unsigned short*)(ws + (16u << 20));

  (void)hipMemsetAsync(a_sum, 0, NB * KK * 4 + NB * 4, stream);
  k0_cvt<<<dim3((KK * CDIM) / 256), 256, 0, stream>>>(cc, ccb);
  k1_assign<<<dim3(16, NB), 256, 0, stream>>>(x, ccb, a_t, xTg, a_sum);
  k2_agg<<<dim3(8, 2, NB), 256, 0, stream>>>(a_t, xTg, cc, a_sum, out, sumsq);
  k3_norm<<<dim3(2048), 256, 0, stream>>>(out, sumsq);
}

// Round 5
// 92.574 us; speedup vs baseline: 1.4637x; 1.4637x over previous
//
#include <hip/hip_runtime.h>
#include <stdint.h>

#define NB 64
#define NN 1024
#define CDIM 512
#define KK 64
#define RS 72   // LDS row stride in ushorts: 144B = 16B-aligned, bank-uniform

typedef __attribute__((ext_vector_type(4))) float f32x4;
typedef __attribute__((ext_vector_type(8))) short short8;
typedef __attribute__((ext_vector_type(4))) unsigned short u16x4;

__device__ __forceinline__ unsigned short f2bf(float f) {
  unsigned int u = __float_as_uint(f);
  return (unsigned short)((u + 0x7fffu + ((u >> 16) & 1u)) >> 16);
}

// ---------------- K0: centers fp32 -> bf16 ----------------
__global__ __launch_bounds__(256) void k0_cvt(const float* __restrict__ cc,
                                              unsigned short* __restrict__ ccb) {
  int i = blockIdx.x * 256 + threadIdx.x;   // grid sized exactly KK*CDIM/256
  ccb[i] = f2bf(cc[i]);
}

// ---------------- K1: logits (MFMA) + softmax + a^T (bf16) + a_sum ----------------
// grid: (16 n-chunks, 64 b), 256 threads = 4 waves, wave owns 16 rows.
__global__ __launch_bounds__(256) void k1_assign(const float* __restrict__ x,
    const unsigned short* __restrict__ ccb, unsigned short* __restrict__ a_t,
    float* __restrict__ a_sum) {
  const int b = blockIdx.y;
  const int n0 = blockIdx.x << 6;
  const int tid = threadIdx.x;
  const int w = tid >> 6;
  const int l = tid & 63;
  const int lr = l & 15;
  const int lg = l >> 4;

  __shared__ unsigned short a_sm[KK * 64];  // [kc][r], byte-swizzled

  const float* xr = x + ((size_t)b * NN + n0 + (w << 4) + lr) * CDIM + (lg << 3);
  const unsigned short* cb = ccb + lr * CDIM + (lg << 3);

  f32x4 acc0 = {0.f, 0.f, 0.f, 0.f}, acc1 = acc0, acc2 = acc0, acc3 = acc0;

  #pragma unroll 2
  for (int cs = 0; cs < CDIM; cs += 32) {
    f32x4 xa = *(const f32x4*)(xr + cs);
    f32x4 xb = *(const f32x4*)(xr + cs + 4);
    short8 af;
    af[0] = (short)f2bf(xa[0]); af[1] = (short)f2bf(xa[1]);
    af[2] = (short)f2bf(xa[2]); af[3] = (short)f2bf(xa[3]);
    af[4] = (short)f2bf(xb[0]); af[5] = (short)f2bf(xb[1]);
    af[6] = (short)f2bf(xb[2]); af[7] = (short)f2bf(xb[3]);
    short8 b0 = *(const short8*)(cb + cs);
    short8 b1 = *(const short8*)(cb + 16 * CDIM + cs);
    short8 b2 = *(const short8*)(cb + 32 * CDIM + cs);
    short8 b3 = *(const short8*)(cb + 48 * CDIM + cs);
    acc0 = __builtin_amdgcn_mfma_f32_16x16x32_bf16(af, b0, acc0, 0, 0, 0);
    acc1 = __builtin_amdgcn_mfma_f32_16x16x32_bf16(af, b1, acc1, 0, 0, 0);
    acc2 = __builtin_amdgcn_mfma_f32_16x16x32_bf16(af, b2, acc2, 0, 0, 0);
    acc3 = __builtin_amdgcn_mfma_f32_16x16x32_bf16(af, b3, acc3, 0, 0, 0);
  }

  // D layout: lane holds logits[row=(l>>4)*4+j][kc=t*16+(l&15)] in acc_t[j]
  const int swzb = (lr & 7) << 3;
  float s0 = 0.f, s1 = 0.f, s2 = 0.f, s3 = 0.f;
  #pragma unroll
  for (int j = 0; j < 4; ++j) {
    float m = fmaxf(fmaxf(acc0[j], acc1[j]), fmaxf(acc2[j], acc3[j]));
    m = fmaxf(m, __shfl_xor(m, 1));
    m = fmaxf(m, __shfl_xor(m, 2));
    m = fmaxf(m, __shfl_xor(m, 4));
    m = fmaxf(m, __shfl_xor(m, 8));
    float e0 = __expf(acc0[j] - m);
    float e1 = __expf(acc1[j] - m);
    float e2 = __expf(acc2[j] - m);
    float e3 = __expf(acc3[j] - m);
    float s = e0 + e1 + e2 + e3;
    s += __shfl_xor(s, 1); s += __shfl_xor(s, 2);
    s += __shfl_xor(s, 4); s += __shfl_xor(s, 8);
    float inv = 1.0f / s;
    e0 *= inv; e1 *= inv; e2 *= inv; e3 *= inv;
    int r = (w << 4) + (lg << 2) + j;
    int rs = r ^ swzb;
    a_sm[( lr       << 6) + rs] = f2bf(e0);
    a_sm[((16 + lr) << 6) + rs] = f2bf(e1);
    a_sm[((32 + lr) << 6) + rs] = f2bf(e2);
    a_sm[((48 + lr) << 6) + rs] = f2bf(e3);
    s0 += e0; s1 += e1; s2 += e2; s3 += e3;
  }
  s0 += __shfl_xor(s0, 16); s0 += __shfl_xor(s0, 32);
  s1 += __shfl_xor(s1, 16); s1 += __shfl_xor(s1, 32);
  s2 += __shfl_xor(s2, 16); s2 += __shfl_xor(s2, 32);
  s3 += __shfl_xor(s3, 16); s3 += __shfl_xor(s3, 32);
  if (lg == 0) {
    atomicAdd(&a_sum[(b << 6) + lr],      s0);
    atomicAdd(&a_sum[(b << 6) + 16 + lr], s1);
    atomicAdd(&a_sum[(b << 6) + 32 + lr], s2);
    atomicAdd(&a_sum[(b << 6) + 48 + lr], s3);
  }
  __syncthreads();
  const unsigned int* au = (const unsigned int*)a_sm;
  for (int e = tid; e < 2048; e += 256) {
    int kc = e >> 5, n2 = e & 31;
    unsigned int v = au[(kc << 5) + (n2 ^ ((kc & 7) << 2))];
    *((unsigned int*)(a_t + (((size_t)((b << 6) + kc)) << 10) + n0) + n2) = v;
  }
}

// ---- K2: agg = a^T x via MFMA, double-buffered padded-LDS, T14 stage split ----
// grid: (8 c-slices, 64 b) = 512 blocks, 256 thr = 4 waves.
// Wave w: k-base (w>>1)*32, c-base (w&1)*32 -> 32k x 32c = 4 acc tiles 16x16.
// Per 64-n chunk: a-tile [64k][64n] staged via short8 copy (n-contiguous);
// xT-tile [64c][64n] staged via 16 scalar f32 + pack + b64 writes.
// Padded rows (RS=72 ush = 144B): 16B-aligned, uniform bank load, no XOR.
__global__ __launch_bounds__(256) void k2_agg(const float* __restrict__ x,
    const unsigned short* __restrict__ a_t, const float* __restrict__ cc,
    const float* __restrict__ a_sum, float* __restrict__ out,
    float* __restrict__ sumsq) {
  const int b = blockIdx.y;
  const int c0 = blockIdx.x << 6;
  const int tid = threadIdx.x;
  const int w = tid >> 6;
  const int l = tid & 63;
  const int lr = l & 15;
  const int lg = l >> 4;
  const int kb = (w >> 1) << 5;
  const int cbl = (w & 1) << 5;

  __shared__ unsigned short aL[2][64 * RS];
  __shared__ unsigned short xL[2][64 * RS];
  __shared__ float red[4];

  f32x4 acc00 = {0.f, 0.f, 0.f, 0.f};
  f32x4 acc01 = acc00, acc10 = acc00, acc11 = acc00;

  // staging maps
  const int cl = tid & 63;              // x-stage: c lane (coalesced)
  const int nq = (tid >> 6) << 2;       // x-stage: n-quad base
  const float* xb = x + (size_t)b * NN * CDIM + c0 + cl;
  const int ak0 = tid >> 3;             // a-stage round 0: k row
  const int ak1 = (tid + 256) >> 3;     // a-stage round 1: k row
  const int aoc = (tid & 7) << 3;       // a-stage: n offset (oct*8)
  const unsigned short* abase = a_t + (((size_t)b) << 16);  // b*64*1024

  // ---- prologue: stage chunk 0 into buf 0 ----
  {
    #pragma unroll
    for (int p = 0; p < 4; ++p) {
      int nl = nq + (p << 4);
      const float* xp = xb + (size_t)nl * CDIM;
      u16x4 pk;
      pk[0] = f2bf(xp[0]);
      pk[1] = f2bf(xp[CDIM]);
      pk[2] = f2bf(xp[2 * CDIM]);
      pk[3] = f2bf(xp[3 * CDIM]);
      *(u16x4*)&xL[0][cl * RS + nl] = pk;
    }
    *(short8*)&aL[0][ak0 * RS + aoc] =
        *(const short8*)(abase + ((size_t)ak0 << 10) + aoc);
    *(short8*)&aL[0][ak1 * RS + aoc] =
        *(const short8*)(abase + ((size_t)ak1 << 10) + aoc);
  }
  __syncthreads();

  for (int it = 0; it < 16; ++it) {
    const int cur = it & 1;
    // T14 phase 1: issue next chunk's global loads into registers
    float xr[16];
    short8 ar0, ar1;
    if (it < 15) {
      const int n0 = (it + 1) << 6;
      #pragma unroll
      for (int p = 0; p < 4; ++p) {
        const float* xp = xb + (size_t)(n0 + nq + (p << 4)) * CDIM;
        xr[p * 4 + 0] = xp[0];
        xr[p * 4 + 1] = xp[CDIM];
        xr[p * 4 + 2] = xp[2 * CDIM];
        xr[p * 4 + 3] = xp[3 * CDIM];
      }
      ar0 = *(const short8*)(abase + ((size_t)ak0 << 10) + n0 + aoc);
      ar1 = *(const short8*)(abase + ((size_t)ak1 << 10) + n0 + aoc);
    }
    // phase 2: compute on buf[cur]
    #pragma unroll
    for (int ns = 0; ns < 64; ns += 32) {
      const int no = ns + (lg << 3);
      short8 a0 = *(const short8*)&aL[cur][(kb + lr) * RS + no];
      short8 a1 = *(const short8*)&aL[cur][(kb + 16 + lr) * RS + no];
      short8 b0 = *(const short8*)&xL[cur][(cbl + lr) * RS + no];
      short8 b1 = *(const short8*)&xL[cur][(cbl + 16 + lr) * RS + no];
      acc00 = __builtin_amdgcn_mfma_f32_16x16x32_bf16(a0, b0, acc00, 0, 0, 0);
      acc01 = __builtin_amdgcn_mfma_f32_16x16x32_bf16(a0, b1, acc01, 0, 0, 0);
      acc10 = __builtin_amdgcn_mfma_f32_16x16x32_bf16(a1, b0, acc10, 0, 0, 0);
      acc11 = __builtin_amdgcn_mfma_f32_16x16x32_bf16(a1, b1, acc11, 0, 0, 0);
    }
    // phase 3: write staged registers into the other buffer
    if (it < 15) {
      const int nxt = cur ^ 1;
      #pragma unroll
      for (int p = 0; p < 4; ++p) {
        int nl = nq + (p << 4);
        u16x4 pk;
        pk[0] = f2bf(xr[p * 4 + 0]);
        pk[1] = f2bf(xr[p * 4 + 1]);
        pk[2] = f2bf(xr[p * 4 + 2]);
        pk[3] = f2bf(xr[p * 4 + 3]);
        *(u16x4*)&xL[nxt][cl * RS + nl] = pk;
      }
      *(short8*)&aL[nxt][ak0 * RS + aoc] = ar0;
      *(short8*)&aL[nxt][ak1 * RS + aoc] = ar1;
    }
    __syncthreads();
  }

  // epilogue: D[row=k][col=c], 16x16 layout: col = lr, row = lg*4+j
  float lsum = 0.f;
  #pragma unroll
  for (int ki = 0; ki < 2; ++ki) {
    #pragma unroll
    for (int ci = 0; ci < 2; ++ci) {
      const f32x4 av = ki == 0 ? (ci == 0 ? acc00 : acc01)
                               : (ci == 0 ? acc10 : acc11);
      #pragma unroll
      for (int j = 0; j < 4; ++j) {
        int k = kb + (ki << 4) + (lg << 2) + j;
        int c = c0 + cbl + (ci << 4) + lr;
        float v = av[j] - a_sum[(b << 6) + k] * cc[k * CDIM + c];
        out[((size_t)b << 15) + (k << 9) + c] = v;
        lsum += v * v;
      }
    }
  }
  lsum += __shfl_xor(lsum, 1);  lsum += __shfl_xor(lsum, 2);
  lsum += __shfl_xor(lsum, 4);  lsum += __shfl_xor(lsum, 8);
  lsum += __shfl_xor(lsum, 16); lsum += __shfl_xor(lsum, 32);
  if (l == 0) red[w] = lsum;
  __syncthreads();
  if (tid == 0) atomicAdd(&sumsq[b], red[0] + red[1] + red[2] + red[3]);
}

// ---------------- K3: l2 normalize per batch ----------------
__global__ __launch_bounds__(256) void k3_norm(float* __restrict__ out,
                                               const float* __restrict__ sumsq) {
  int idx = blockIdx.x * 256 + threadIdx.x;   // grid exact: 2048*256 = 2M/4
  int b = idx >> 13;                          // 8192 float4 per batch
  float s = sumsq[b];
  float scale = 1.0f / sqrtf(fmaxf(s, 1e-12f));
  f32x4* io = (f32x4*)out;
  f32x4 v = io[idx];
  v[0] *= scale; v[1] *= scale; v[2] *= scale; v[3] *= scale;
  io[idx] = v;
}

extern "C" void kernel_launch(void* const* d_in, const int* in_sizes, int n_in,
                              void* d_out, int out_size, void* d_ws, size_t ws_size,
                              hipStream_t stream) {
  const float* x  = (const float*)d_in[0];
  const float* cc = (const float*)d_in[1];
  float* out = (float*)d_out;
  char* ws = (char*)d_ws;
  // ws layout: [a_t bf16 8MiB][ccb bf16 64KiB][a_sum 16KiB][sumsq 256B]
  unsigned short* a_t = (unsigned short*)ws;
  unsigned short* ccb = (unsigned short*)(ws + (8u << 20));
  float* a_sum = (float*)(ws + (8u << 20) + (64u << 10));
  float* sumsq = a_sum + NB * KK;

  (void)hipMemsetAsync(a_sum, 0, NB * KK * 4 + NB * 4, stream);
  k0_cvt<<<dim3((KK * CDIM) / 256), 256, 0, stream>>>(cc, ccb);
  k1_assign<<<dim3(16, NB), 256, 0, stream>>>(x, ccb, a_t, a_sum);
  k2_agg<<<dim3(8, NB), 256, 0, stream>>>(x, a_t, cc, a_sum, out, sumsq);
  k3_norm<<<dim3(2048), 256, 0, stream>>>(out, sumsq);
}

// Round 6
// 89.677 us; speedup vs baseline: 1.5110x; 1.0323x over previous
//
#include <hip/hip_runtime.h>
#include <stdint.h>

#define NB 64
#define NN 1024
#define CDIM 512
#define KK 64
#define RS 72   // LDS row stride in ushorts: 144B = 9*16B -> 16B-aligned rows

typedef __attribute__((ext_vector_type(4))) float f32x4;
typedef __attribute__((ext_vector_type(8))) short short8;
typedef __attribute__((ext_vector_type(4))) unsigned short u16x4;

__device__ __forceinline__ unsigned short f2bf(float f) {
  unsigned int u = __float_as_uint(f);
  return (unsigned short)((u + 0x7fffu + ((u >> 16) & 1u)) >> 16);
}

// ---------------- K0: centers fp32 -> bf16 ----------------
__global__ __launch_bounds__(256) void k0_cvt(const float* __restrict__ cc,
                                              unsigned short* __restrict__ ccb) {
  int i = blockIdx.x * 256 + threadIdx.x;   // grid sized exactly KK*CDIM/256
  ccb[i] = f2bf(cc[i]);
}

// ---------------- K1: logits (MFMA) + softmax + a^T (bf16) + a_sum ----------------
// grid: (16 n-chunks, 64 b), 256 threads = 4 waves, wave owns 16 rows.
__global__ __launch_bounds__(256) void k1_assign(const float* __restrict__ x,
    const unsigned short* __restrict__ ccb, unsigned short* __restrict__ a_t,
    float* __restrict__ a_sum) {
  const int b = blockIdx.y;
  const int n0 = blockIdx.x << 6;
  const int tid = threadIdx.x;
  const int w = tid >> 6;
  const int l = tid & 63;
  const int lr = l & 15;
  const int lg = l >> 4;

  __shared__ unsigned short a_sm[KK * 64];  // [kc][r], byte-swizzled

  const float* xr = x + ((size_t)b * NN + n0 + (w << 4) + lr) * CDIM + (lg << 3);
  const unsigned short* cb = ccb + lr * CDIM + (lg << 3);

  f32x4 acc0 = {0.f, 0.f, 0.f, 0.f}, acc1 = acc0, acc2 = acc0, acc3 = acc0;

  #pragma unroll 2
  for (int cs = 0; cs < CDIM; cs += 32) {
    f32x4 xa = *(const f32x4*)(xr + cs);
    f32x4 xb = *(const f32x4*)(xr + cs + 4);
    short8 af;
    af[0] = (short)f2bf(xa[0]); af[1] = (short)f2bf(xa[1]);
    af[2] = (short)f2bf(xa[2]); af[3] = (short)f2bf(xa[3]);
    af[4] = (short)f2bf(xb[0]); af[5] = (short)f2bf(xb[1]);
    af[6] = (short)f2bf(xb[2]); af[7] = (short)f2bf(xb[3]);
    short8 b0 = *(const short8*)(cb + cs);
    short8 b1 = *(const short8*)(cb + 16 * CDIM + cs);
    short8 b2 = *(const short8*)(cb + 32 * CDIM + cs);
    short8 b3 = *(const short8*)(cb + 48 * CDIM + cs);
    acc0 = __builtin_amdgcn_mfma_f32_16x16x32_bf16(af, b0, acc0, 0, 0, 0);
    acc1 = __builtin_amdgcn_mfma_f32_16x16x32_bf16(af, b1, acc1, 0, 0, 0);
    acc2 = __builtin_amdgcn_mfma_f32_16x16x32_bf16(af, b2, acc2, 0, 0, 0);
    acc3 = __builtin_amdgcn_mfma_f32_16x16x32_bf16(af, b3, acc3, 0, 0, 0);
  }

  // D layout: lane holds logits[row=(l>>4)*4+j][kc=t*16+(l&15)] in acc_t[j]
  const int swzb = (lr & 7) << 3;
  float s0 = 0.f, s1 = 0.f, s2 = 0.f, s3 = 0.f;
  #pragma unroll
  for (int j = 0; j < 4; ++j) {
    float m = fmaxf(fmaxf(acc0[j], acc1[j]), fmaxf(acc2[j], acc3[j]));
    m = fmaxf(m, __shfl_xor(m, 1));
    m = fmaxf(m, __shfl_xor(m, 2));
    m = fmaxf(m, __shfl_xor(m, 4));
    m = fmaxf(m, __shfl_xor(m, 8));
    float e0 = __expf(acc0[j] - m);
    float e1 = __expf(acc1[j] - m);
    float e2 = __expf(acc2[j] - m);
    float e3 = __expf(acc3[j] - m);
    float s = e0 + e1 + e2 + e3;
    s += __shfl_xor(s, 1); s += __shfl_xor(s, 2);
    s += __shfl_xor(s, 4); s += __shfl_xor(s, 8);
    float inv = 1.0f / s;
    e0 *= inv; e1 *= inv; e2 *= inv; e3 *= inv;
    int r = (w << 4) + (lg << 2) + j;
    int rs = r ^ swzb;
    a_sm[( lr       << 6) + rs] = f2bf(e0);
    a_sm[((16 + lr) << 6) + rs] = f2bf(e1);
    a_sm[((32 + lr) << 6) + rs] = f2bf(e2);
    a_sm[((48 + lr) << 6) + rs] = f2bf(e3);
    s0 += e0; s1 += e1; s2 += e2; s3 += e3;
  }
  s0 += __shfl_xor(s0, 16); s0 += __shfl_xor(s0, 32);
  s1 += __shfl_xor(s1, 16); s1 += __shfl_xor(s1, 32);
  s2 += __shfl_xor(s2, 16); s2 += __shfl_xor(s2, 32);
  s3 += __shfl_xor(s3, 16); s3 += __shfl_xor(s3, 32);
  if (lg == 0) {
    atomicAdd(&a_sum[(b << 6) + lr],      s0);
    atomicAdd(&a_sum[(b << 6) + 16 + lr], s1);
    atomicAdd(&a_sum[(b << 6) + 32 + lr], s2);
    atomicAdd(&a_sum[(b << 6) + 48 + lr], s3);
  }
  __syncthreads();
  const unsigned int* au = (const unsigned int*)a_sm;
  for (int e = tid; e < 2048; e += 256) {
    int kc = e >> 5, n2 = e & 31;
    unsigned int v = au[(kc << 5) + (n2 ^ ((kc & 7) << 2))];
    *((unsigned int*)(a_t + (((size_t)((b << 6) + kc)) << 10) + n0) + n2) = v;
  }
}

// ---- K2: agg = a^T x via MFMA. c-slice 128, A direct-from-global, xT-only LDS ----
// grid: (4 c-slices, 64 b) = 256 blocks, 256 thr = 4 waves, 4 blocks/CU.
// Wave w: k-rows [16w,16w+16), all 128 c (8 tiles of 16). Per 64-n chunk:
// xT tile [128 c][64 n] bf16 staged via 32 scalar fp32 loads/thread (coalesced)
// packed to 4x short8 b128 LDS writes. T14: next chunk's loads (x fp32 + a
// frags) issue before current chunk's MFMA; writes land after.
__global__ __launch_bounds__(256, 4) void k2_agg(const float* __restrict__ x,
    const unsigned short* __restrict__ a_t, const float* __restrict__ cc,
    const float* __restrict__ a_sum, float* __restrict__ out,
    float* __restrict__ sumsq) {
  const int b = blockIdx.y;
  const int c0 = blockIdx.x << 7;
  const int tid = threadIdx.x;
  const int w = tid >> 6;
  const int l = tid & 63;
  const int lr = l & 15;
  const int lg = l >> 4;

  __shared__ unsigned short xL[2][128 * RS];
  __shared__ float red[4];

  f32x4 acc[8];
  #pragma unroll
  for (int i = 0; i < 8; ++i) acc[i] = (f32x4){0.f, 0.f, 0.f, 0.f};

  // stage map: cl = tid&127 (c lane, coalesced), octets o = (tid>>7)*4 + p
  const int cl = tid & 127;
  const int ob = (tid >> 7) << 2;       // octet base: 0 or 4
  const float* xb = x + (size_t)b * NN * CDIM + c0 + cl;
  // A-frag pointer: row k = 16w + lr, n offset lg*8
  const unsigned short* ap =
      a_t + (((size_t)((b << 6) + (w << 4) + lr)) << 10) + (lg << 3);

  // ---- prologue: stage chunk 0 + load chunk-0 A-frags ----
  #pragma unroll
  for (int p = 0; p < 4; ++p) {
    const int nl = (ob + p) << 3;
    const float* xp = xb + (size_t)nl * CDIM;
    short8 pk;
    #pragma unroll
    for (int q = 0; q < 8; ++q) pk[q] = (short)f2bf(xp[(size_t)q * CDIM]);
    *(short8*)&xL[0][cl * RS + nl] = pk;
  }
  short8 a_cur0 = *(const short8*)(ap);
  short8 a_cur1 = *(const short8*)(ap + 32);
  __syncthreads();

  for (int it = 0; it < 16; ++it) {
    const int cur = it & 1;
    // T14 phase 1: issue next chunk's global loads
    float xr[32];
    short8 a_nxt0, a_nxt1;
    if (it < 15) {
      const int n0 = (it + 1) << 6;
      #pragma unroll
      for (int p = 0; p < 4; ++p) {
        const float* xp = xb + (size_t)(n0 + ((ob + p) << 3)) * CDIM;
        #pragma unroll
        for (int q = 0; q < 8; ++q) xr[p * 8 + q] = xp[(size_t)q * CDIM];
      }
      a_nxt0 = *(const short8*)(ap + n0);
      a_nxt1 = *(const short8*)(ap + n0 + 32);
    }
    // phase 2: MFMA on buf[cur]; 2 k-steps x 8 c-tiles
    #pragma unroll
    for (int ns = 0; ns < 64; ns += 32) {
      const short8 af = ns == 0 ? a_cur0 : a_cur1;
      #pragma unroll
      for (int ct = 0; ct < 8; ++ct) {
        const int row = (ct << 4) + lr;
        short8 bf = *(const short8*)&xL[cur][row * RS + ns + (lg << 3)];
        acc[ct] = __builtin_amdgcn_mfma_f32_16x16x32_bf16(af, bf, acc[ct], 0, 0, 0);
      }
    }
    // phase 3: pack + write staged regs into other buffer
    if (it < 15) {
      const int nxt = cur ^ 1;
      #pragma unroll
      for (int p = 0; p < 4; ++p) {
        const int nl = (ob + p) << 3;
        short8 pk;
        #pragma unroll
        for (int q = 0; q < 8; ++q) pk[q] = (short)f2bf(xr[p * 8 + q]);
        *(short8*)&xL[nxt][cl * RS + nl] = pk;
      }
      a_cur0 = a_nxt0;
      a_cur1 = a_nxt1;
    }
    __syncthreads();
  }

  // epilogue: tile ct: D[row=k=16w+lg*4+j][col=c=c0+ct*16+lr]
  float lsum = 0.f;
  #pragma unroll
  for (int ct = 0; ct < 8; ++ct) {
    #pragma unroll
    for (int j = 0; j < 4; ++j) {
      int k = (w << 4) + (lg << 2) + j;
      int c = c0 + (ct << 4) + lr;
      float v = acc[ct][j] - a_sum[(b << 6) + k] * cc[k * CDIM + c];
      out[((size_t)b << 15) + (k << 9) + c] = v;
      lsum += v * v;
    }
  }
  lsum += __shfl_xor(lsum, 1);  lsum += __shfl_xor(lsum, 2);
  lsum += __shfl_xor(lsum, 4);  lsum += __shfl_xor(lsum, 8);
  lsum += __shfl_xor(lsum, 16); lsum += __shfl_xor(lsum, 32);
  if (l == 0) red[w] = lsum;
  __syncthreads();
  if (tid == 0) atomicAdd(&sumsq[b], red[0] + red[1] + red[2] + red[3]);
}

// ---------------- K3: l2 normalize per batch ----------------
__global__ __launch_bounds__(256) void k3_norm(float* __restrict__ out,
                                               const float* __restrict__ sumsq) {
  int idx = blockIdx.x * 256 + threadIdx.x;   // grid exact: 2048*256 = 2M/4
  int b = idx >> 13;                          // 8192 float4 per batch
  float s = sumsq[b];
  float scale = 1.0f / sqrtf(fmaxf(s, 1e-12f));
  f32x4* io = (f32x4*)out;
  f32x4 v = io[idx];
  v[0] *= scale; v[1] *= scale; v[2] *= scale; v[3] *= scale;
  io[idx] = v;
}

extern "C" void kernel_launch(void* const* d_in, const int* in_sizes, int n_in,
                              void* d_out, int out_size, void* d_ws, size_t ws_size,
                              hipStream_t stream) {
  const float* x  = (const float*)d_in[0];
  const float* cc = (const float*)d_in[1];
  float* out = (float*)d_out;
  char* ws = (char*)d_ws;
  // ws layout: [a_t bf16 8MiB][ccb bf16 64KiB][a_sum 16KiB][sumsq 256B]
  unsigned short* a_t = (unsigned short*)ws;
  unsigned short* ccb = (unsigned short*)(ws + (8u << 20));
  float* a_sum = (float*)(ws + (8u << 20) + (64u << 10));
  float* sumsq = a_sum + NB * KK;

  (void)hipMemsetAsync(a_sum, 0, NB * KK * 4 + NB * 4, stream);
  k0_cvt<<<dim3((KK * CDIM) / 256), 256, 0, stream>>>(cc, ccb);
  k1_assign<<<dim3(16, NB), 256, 0, stream>>>(x, ccb, a_t, a_sum);
  k2_agg<<<dim3(4, NB), 256, 0, stream>>>(x, a_t, cc, a_sum, out, sumsq);
  k3_norm<<<dim3(2048), 256, 0, stream>>>(out, sumsq);
}